// Round 4
// baseline (21122.574 us; speedup 1.0000x reference)
//
#include <hip/hip_runtime.h>
#include <hip/hip_bf16.h>

// NSSNN forward on MI355X. x (1,1,31,96,96) fp32. S = 31*96*96 = 285696.
// Chunked conv->scan pipeline (round-3 PASS structure) with register-blocked
// direct conv: 32x32 spatial tile / block, 2x2 micro-tile / thread, 8 oc.
// Weights read from global with wave-uniform addresses (scalarizable), input
// from LDS via contiguous (b64-mergeable) reads -> VALU-bound instead of
// LDS-read-bound.
// Workspace arena: g(48*S) | h(16*S) | e0(32*S) | e1(64*S); d0 in-place over
// e0, d1 over dead e1. fp32: 183 MB; bf16 storage fallback: 91 MB.

#define D_DIM 31
#define H_DIM 96
#define W_DIM 96
#define HW (H_DIM * W_DIM)
#define SVOX (D_DIM * HW)

__device__ __forceinline__ float sigm(float v) { return 1.0f / (1.0f + __expf(-v)); }

template <typename T> __device__ __forceinline__ float ldf(const T* p);
template <> __device__ __forceinline__ float ldf<float>(const float* p) { return *p; }
template <> __device__ __forceinline__ float ldf<__hip_bfloat16>(const __hip_bfloat16* p) {
    return __bfloat162float(*p);
}
template <typename T> __device__ __forceinline__ void stf(T* p, float v);
template <> __device__ __forceinline__ void stf<float>(float* p, float v) { *p = v; }
template <> __device__ __forceinline__ void stf<__hip_bfloat16>(__hip_bfloat16* p, float v) {
    *p = __float2bfloat16(v);
}

// ---------------------------------------------------------------------------
// Direct 3x3x3 conv, pad 1. Block: 256 thr, 32x32 (h,w) tile, one depth slice,
// BC output channels of ONE gate group (blockIdx.z). Each thread: 2x2 spatial
// micro-tile x BC oc accumulators.
// deconv: weight (C_in, C_out_w, 27) flipped -> w[(ci*C_out_w + oc)*27 + 26-kk]
// normal: weight (C_out_w, C_in, 27)         -> w[(oc*C_in + ci)*27 + kk]
// ---------------------------------------------------------------------------
template <typename Tin, typename Tout, int BC>
__global__ __launch_bounds__(256) void conv3d_k(const Tin* __restrict__ x,
                                                const float* __restrict__ w,
                                                Tout* __restrict__ out,
                                                int C_in, int C_out_w, int Ch, int c0,
                                                int deconv) {
    __shared__ float tile[3][34][36];  // [dz][row][col], ~14.7 KB

    const int t = threadIdx.x;
    const int lx = t & 15;       // 0..15 -> cols lx*2, lx*2+1
    const int ly = t >> 4;       // 0..15 -> rows ly*2, ly*2+1
    const int tbx = (blockIdx.x % 3) * 32;
    const int tby = (blockIdx.x / 3) * 32;
    const int d = blockIdx.y;
    const int gidx = blockIdx.z;
    const int ocw0 = gidx * Ch + c0;  // weight-space out-channel base
    const int oco0 = gidx * BC;       // compact output channel base

    float acc[BC][4];
#pragma unroll
    for (int o = 0; o < BC; ++o)
#pragma unroll
        for (int p = 0; p < 4; ++p) acc[o][p] = 0.0f;

    for (int ci = 0; ci < C_in; ++ci) {
        __syncthreads();  // protect LDS from previous iteration's readers
        const Tin* xc = x + (size_t)ci * SVOX;
        for (int i = t; i < 3 * 34 * 34; i += 256) {
            int dz = i / 1156;
            int rem = i - dz * 1156;
            int r = rem / 34;
            int c = rem - r * 34;
            int gd = d + dz - 1;
            int gy = tby + r - 1;
            int gx = tbx + c - 1;
            float v = 0.0f;
            if ((unsigned)gd < D_DIM && (unsigned)gy < H_DIM && (unsigned)gx < W_DIM)
                v = ldf(xc + ((size_t)gd * H_DIM + gy) * W_DIM + gx);
            tile[dz][r][c] = v;
        }
        __syncthreads();

#pragma unroll
        for (int kd = 0; kd < 3; ++kd) {
#pragma unroll
            for (int kh = 0; kh < 3; ++kh) {
                // weights: wave-uniform global reads (scalarizable)
                float wv[BC][3];
#pragma unroll
                for (int o = 0; o < BC; ++o)
#pragma unroll
                    for (int kw = 0; kw < 3; ++kw) {
                        const int kk = (kd * 3 + kh) * 3 + kw;
                        wv[o][kw] = deconv
                            ? w[((size_t)ci * C_out_w + ocw0 + o) * 27 + (26 - kk)]
                            : w[((size_t)(ocw0 + o) * C_in + ci) * 27 + kk];
                    }
                // input: 2 rows x 4 contiguous cols from LDS (merges to b64)
                const int r0 = ly * 2 + kh;
                float v0[4], v1[4];
#pragma unroll
                for (int c = 0; c < 4; ++c) {
                    v0[c] = tile[kd][r0][lx * 2 + c];
                    v1[c] = tile[kd][r0 + 1][lx * 2 + c];
                }
#pragma unroll
                for (int kw = 0; kw < 3; ++kw)
#pragma unroll
                    for (int o = 0; o < BC; ++o) {
                        acc[o][0] = fmaf(v0[kw],     wv[o][kw], acc[o][0]);
                        acc[o][1] = fmaf(v0[kw + 1], wv[o][kw], acc[o][1]);
                        acc[o][2] = fmaf(v1[kw],     wv[o][kw], acc[o][2]);
                        acc[o][3] = fmaf(v1[kw + 1], wv[o][kw], acc[o][3]);
                    }
            }
        }
    }

    const int hy = tby + ly * 2, wx = tbx + lx * 2;
#pragma unroll
    for (int o = 0; o < BC; ++o) {
        Tout* op = out + (size_t)(oco0 + o) * SVOX + (size_t)d * HW;
        stf(op + (hy + 0) * W_DIM + wx + 0, acc[o][0]);
        stf(op + (hy + 0) * W_DIM + wx + 1, acc[o][1]);
        stf(op + (hy + 1) * W_DIM + wx + 0, acc[o][2]);
        stf(op + (hy + 1) * W_DIM + wx + 1, acc[o][3]);
    }
}

// ---------------------------------------------------------------------------
// do_sru scan on a chunk: g compact (6*chunk, D, H, W), groups [Wx,ft,ft2,rt,rt2,X].
// out[(c0+c)] = fwd + rev (+ resid). One thread per (c,h,w) column.
// ---------------------------------------------------------------------------
template <typename Tg, typename Tio>
__global__ __launch_bounds__(256) void do_sru_scan_k(const Tg* __restrict__ g,
                                                     const Tio* __restrict__ resid,
                                                     Tio* __restrict__ out,
                                                     int chunk, int c0) {
    int idx = blockIdx.x * blockDim.x + threadIdx.x;
    if (idx >= chunk * HW) return;
    int c = idx / HW, hw = idx % HW;
    const size_t gbase = (size_t)c * SVOX + hw;
    const size_t gs = (size_t)chunk * SVOX;
    const size_t obase = (size_t)(c0 + c) * SVOX + hw;
    const Tg* gW = g + gbase;
    const Tg* gF = g + gs + gbase;
    const Tg* gF2 = g + 2 * gs + gbase;
    const Tg* gR = g + 3 * gs + gbase;
    const Tg* gR2 = g + 4 * gs + gbase;
    const Tg* gX = g + 5 * gs + gbase;

    float hbuf[D_DIM];
    float C = 0.0f;
#pragma unroll
    for (int d = 0; d < D_DIM; ++d) {
        float f = sigm(ldf(gF + d * HW));
        float r = sigm(ldf(gR + d * HW));
        float xv = tanhf(ldf(gX + d * HW));
        float wv = tanhf(ldf(gW + d * HW));
        C = (d == 0) ? (1.0f - f) : (f * C + (1.0f - f) * wv);
        hbuf[d] = r * C + (1.0f - r) * xv;
    }
#pragma unroll
    for (int i = 0; i < D_DIM; ++i) {
        int d = D_DIM - 1 - i;
        float f = sigm(ldf(gF2 + d * HW));
        float r = sigm(ldf(gR2 + d * HW));
        float xv = tanhf(ldf(gX + d * HW));
        float wv = tanhf(ldf(gW + d * HW));
        C = (i == 0) ? (1.0f - f) : (f * C + (1.0f - f) * wv);
        float hv = r * C + (1.0f - r) * xv;
        float res = resid ? ldf(resid + obase + d * HW) : 0.0f;
        hbuf[d] += hv + res;
    }
#pragma unroll
    for (int d = 0; d < D_DIM; ++d) stf(out + obase + d * HW, hbuf[d]);
}

// ---------------------------------------------------------------------------
// si_sru scan on a chunk: g compact (4*chunk, D, H, W), groups [Wx,ft,rt,X].
// Reads resid then writes out at the same element -> safe when out==resid.
// ---------------------------------------------------------------------------
template <typename T, int REV>
__global__ __launch_bounds__(256) void si_sru_scan_k(const T* __restrict__ g,
                                                     const T* __restrict__ resid,
                                                     T* __restrict__ out,
                                                     int chunk, int c0) {
    int idx = blockIdx.x * blockDim.x + threadIdx.x;
    if (idx >= chunk * HW) return;
    int c = idx / HW, hw = idx % HW;
    const size_t gbase = (size_t)c * SVOX + hw;
    const size_t gs = (size_t)chunk * SVOX;
    const size_t obase = (size_t)(c0 + c) * SVOX + hw;
    const T* gW = g + gbase;
    const T* gF = g + gs + gbase;
    const T* gR = g + 2 * gs + gbase;
    const T* gX = g + 3 * gs + gbase;

    float C = 0.0f;
#pragma unroll
    for (int i = 0; i < D_DIM; ++i) {
        int d = REV ? (D_DIM - 1 - i) : i;
        float f = sigm(ldf(gF + d * HW));
        float r = sigm(ldf(gR + d * HW));
        float xv = tanhf(ldf(gX + d * HW));
        float wv = tanhf(ldf(gW + d * HW));
        C = (i == 0) ? (1.0f - f) : (f * C + (1.0f - f) * wv);
        float hv = r * C + (1.0f - r) * xv;
        float o = hv + (resid ? ldf(resid + obase + d * HW) : 0.0f);
        stf(out + obase + d * HW, o);
    }
}

// ---------------------------------------------------------------------------
template <typename T>
static void run_net(const float* x, const float* w_head, const float* w_e0,
                    const float* w_e1, const float* w_d0, const float* w_d1,
                    const float* w_tail, float* out, void* d_ws, hipStream_t stream) {
    T* g  = (T*)d_ws;                 // 48*S
    T* H  = g + (size_t)48 * SVOX;    // 16*S
    T* E0 = H + (size_t)16 * SVOX;    // 32*S (d0 written in-place here)
    T* E1 = E0 + (size_t)32 * SVOX;   // 64*S (d1 aliases first 16*S)
    T* D0 = E0;
    T* D1 = E1;

    dim3 blk(256);
    const dim3 sg8(8 * 36);  // 8*HW/256 blocks
    const dim3 cg(9, 31, 4); // conv grid: 3x3 tiles of 32, 31 depth, 4 groups

    // 1. head: conv 1->96 (Ch=16, 6 groups), do_sru -> H
    for (int c0 = 0; c0 < 16; c0 += 8) {
        conv3d_k<float, T, 8><<<dim3(9, 31, 6), blk, 0, stream>>>(x, w_head, g, 1, 96, 16, c0, 0);
        do_sru_scan_k<T, T><<<sg8, blk, 0, stream>>>(g, (const T*)nullptr, H, 8, c0);
    }
    // 2. e0: conv 16->128 (Ch=32, 4 groups), si_sru fwd -> E0
    for (int c0 = 0; c0 < 32; c0 += 8) {
        conv3d_k<T, T, 8><<<cg, blk, 0, stream>>>(H, w_e0, g, 16, 128, 32, c0, 0);
        si_sru_scan_k<T, 0><<<sg8, blk, 0, stream>>>(g, (const T*)nullptr, E0, 8, c0);
    }
    // 3. e1: conv 32->256 (Ch=64, 4 groups), si_sru rev -> E1
    for (int c0 = 0; c0 < 64; c0 += 8) {
        conv3d_k<T, T, 8><<<cg, blk, 0, stream>>>(E0, w_e1, g, 32, 256, 64, c0, 0);
        si_sru_scan_k<T, 1><<<sg8, blk, 0, stream>>>(g, (const T*)nullptr, E1, 8, c0);
    }
    // 4. d0: deconv 64->128 (Ch=32), si_sru fwd + e0 -> D0 (in-place over E0)
    for (int c0 = 0; c0 < 32; c0 += 8) {
        conv3d_k<T, T, 8><<<cg, blk, 0, stream>>>(E1, w_d0, g, 64, 128, 32, c0, 1);
        si_sru_scan_k<T, 0><<<sg8, blk, 0, stream>>>(g, E0, D0, 8, c0);
    }
    // 5. d1: deconv 32->64 (Ch=16), si_sru rev + h -> D1 (over dead E1)
    for (int c0 = 0; c0 < 16; c0 += 8) {
        conv3d_k<T, T, 8><<<cg, blk, 0, stream>>>(D0, w_d1, g, 32, 64, 16, c0, 1);
        si_sru_scan_k<T, 1><<<sg8, blk, 0, stream>>>(g, H, D1, 8, c0);
    }
    // 6. tail: deconv 16->6 (Ch=1, 6 groups of 1), do_sru + x -> out (fp32)
    conv3d_k<T, T, 1><<<dim3(9, 31, 6), blk, 0, stream>>>(D1, w_tail, g, 16, 6, 1, 0, 1);
    do_sru_scan_k<T, float><<<dim3(36), blk, 0, stream>>>(g, x, out, 1, 0);
}

extern "C" void kernel_launch(void* const* d_in, const int* in_sizes, int n_in,
                              void* d_out, int out_size, void* d_ws, size_t ws_size,
                              hipStream_t stream) {
    const float* x      = (const float*)d_in[0];
    const float* w_head = (const float*)d_in[1];  // (96, 1, 27)
    const float* w_e0   = (const float*)d_in[2];  // (128, 16, 27)
    const float* w_e1   = (const float*)d_in[3];  // (256, 32, 27)
    const float* w_d0   = (const float*)d_in[4];  // (64, 128, 27)  deconv
    const float* w_d1   = (const float*)d_in[5];  // (32, 64, 27)   deconv
    const float* w_tail = (const float*)d_in[6];  // (16, 6, 27)    deconv
    float* out = (float*)d_out;

    const size_t need_f32 = (size_t)160 * SVOX * sizeof(float);  // ~183 MB
    if (ws_size >= need_f32)
        run_net<float>(x, w_head, w_e0, w_e1, w_d0, w_d1, w_tail, out, d_ws, stream);
    else
        run_net<__hip_bfloat16>(x, w_head, w_e0, w_e1, w_d0, w_d1, w_tail, out, d_ws, stream);
}

// Round 5
// 3349.470 us; speedup vs baseline: 6.3062x; 6.3062x over previous
//
#include <hip/hip_runtime.h>
#include <hip/hip_bf16.h>

// NSSNN forward on MI355X. x (1,1,31,96,96) fp32. S = 31*96*96 = 285696.
// Round-5: bf16 MFMA implicit-GEMM conv for the 4 mid layers (e0/e1/d0/d1 =
// 315 of 318 GFLOP); head/tail stay round-3 direct conv. Chunked conv->scan
// pipeline and bf16 workspace arena identical to the round-3 PASS:
//   g(48*S) | h(16*S) | e0(32*S) | e1(64*S)  bf16 = 91.4 MB
// si-layer convs write only 32*S of g; wt (transformed weights, <=432KB)
// lives in g+32S..48S which head/tail don't touch while wt is live.

#define D_DIM 31
#define H_DIM 96
#define W_DIM 96
#define HW (H_DIM * W_DIM)
#define SVOX (D_DIM * HW)

typedef __hip_bfloat16 bf16;
typedef __attribute__((ext_vector_type(8))) short short8;
typedef __attribute__((ext_vector_type(4))) float f32x4;

__device__ __forceinline__ float sigm(float v) { return 1.0f / (1.0f + __expf(-v)); }

template <typename T> __device__ __forceinline__ float ldf(const T* p);
template <> __device__ __forceinline__ float ldf<float>(const float* p) { return *p; }
template <> __device__ __forceinline__ float ldf<bf16>(const bf16* p) {
    return __bfloat162float(*p);
}
template <typename T> __device__ __forceinline__ void stf(T* p, float v);
template <> __device__ __forceinline__ void stf<float>(float* p, float v) { *p = v; }
template <> __device__ __forceinline__ void stf<bf16>(bf16* p, float v) {
    *p = __float2bfloat16(v);
}

// ---------------------------------------------------------------------------
// Weight transform: wt[chunk][kk][oc_c(32)][ci(cip)] bf16, zero-padded ci>=C_in.
// oc_w = (oc_c>>3)*Ch + chunk*8 + (oc_c&7).
// normal: w (C_out_w, C_in, 27);  deconv: w (C_in, C_out_w, 27) + spatial flip.
// ---------------------------------------------------------------------------
__global__ __launch_bounds__(256) void wtrans_k(const float* __restrict__ w,
                                                bf16* __restrict__ wt,
                                                int C_in, int C_out_w, int Ch,
                                                int deconv, int cip, int total) {
    int i = blockIdx.x * 256 + threadIdx.x;
    if (i >= total) return;
    int ci = i % cip;
    int r = i / cip;
    int oc_c = r & 31; r >>= 5;
    int kk = r % 27;
    int chunk = r / 27;
    int oc_w = (oc_c >> 3) * Ch + chunk * 8 + (oc_c & 7);
    float v = 0.0f;
    if (ci < C_in)
        v = deconv ? w[((size_t)ci * C_out_w + oc_w) * 27 + (26 - kk)]
                   : w[((size_t)oc_w * C_in + ci) * 27 + kk];
    wt[i] = __float2bfloat16(v);
}

// ---------------------------------------------------------------------------
// MFMA implicit-GEMM conv: block = one (d,h) output row (96 w) x 32 compact oc.
// 4 waves: wave -> N-tile nt = wave>>1 (16 oc), M-tiles mt0..mt0+2 (3x16 w).
// Per (kd,kh): stage input row [98 w][KB*40 ci] bf16 in LDS (pad-40 stride =
// 80 B: 16B-aligned b128, gcd(20,32)=4 bank spread); 3 kw taps = shifted
// B-frag reads. A-frags: 16B loads from wt (L2-resident, every block same).
// mfma_f32_16x16x32_bf16: A[16 oc x 32 ci] * B[32 ci x 16 w];
// D: oc = (lane>>4)*4 + reg, w = lane&15  [m89-verified layout].
// ---------------------------------------------------------------------------
template <int KB>
__global__ __launch_bounds__(256) void conv_mfma_k(const bf16* __restrict__ x,
                                                   const bf16* __restrict__ wt,
                                                   bf16* __restrict__ out, int C_in) {
    constexpr int RS = KB * 40;  // LDS row stride in bf16 elems (80 B per 32-ci block)
    __shared__ short row[98 * RS];

    const int t = threadIdx.x;
    const int lane = t & 63, wave = t >> 6;
    const int l15 = lane & 15, g4 = lane >> 4;
    const int h = blockIdx.x, d = blockIdx.y;
    const int nt = wave >> 1;        // 0..1: oc tile
    const int mt0 = (wave & 1) * 3;  // 0 or 3: first of 3 w-tiles

    f32x4 acc[3];
#pragma unroll
    for (int m = 0; m < 3; ++m) acc[m] = (f32x4){0.f, 0.f, 0.f, 0.f};

    for (int kd = 0; kd < 3; ++kd) {
        const int dd = d + kd - 1;
        for (int kh = 0; kh < 3; ++kh) {
            const int hh = h + kh - 1;
            __syncthreads();  // protect LDS from previous stage's readers
            const bool rowin = (unsigned)dd < D_DIM && (unsigned)hh < H_DIM;
            for (int i = t; i < 98 * KB * 32; i += 256) {
                int wp = i % 98;
                int cc = i / 98;
                int cb = cc >> 5, ci = cc & 31;
                int cig = cb * 32 + ci;
                int gw = wp - 1;
                float v = 0.0f;
                if (rowin && (unsigned)gw < W_DIM && cig < C_in)
                    v = __bfloat162float(
                        x[(size_t)cig * SVOX + (size_t)dd * HW + hh * W_DIM + gw]);
                bf16 hv = __float2bfloat16(v);
                row[wp * RS + cb * 40 + ci] = *(short*)&hv;
            }
            __syncthreads();

            for (int cb = 0; cb < KB; ++cb) {
#pragma unroll
                for (int kw = 0; kw < 3; ++kw) {
                    const int kk = (kd * 3 + kh) * 3 + kw;
                    short8 a = *(const short8*)(wt +
                        ((size_t)(kk * 32 + nt * 16 + l15) * (KB * 32) + cb * 32 + g4 * 8));
#pragma unroll
                    for (int m = 0; m < 3; ++m) {
                        const int wp = (mt0 + m) * 16 + l15 + kw;
                        short8 b = *(const short8*)(row + wp * RS + cb * 40 + g4 * 8);
                        acc[m] = __builtin_amdgcn_mfma_f32_16x16x32_bf16(a, b, acc[m], 0, 0, 0);
                    }
                }
            }
        }
    }

    // D layout: oc = nt*16 + g4*4 + r, w = (mt0+m)*16 + l15
#pragma unroll
    for (int m = 0; m < 3; ++m) {
        const int wx = (mt0 + m) * 16 + l15;
#pragma unroll
        for (int r = 0; r < 4; ++r) {
            const int oc = nt * 16 + g4 * 4 + r;
            stf(out + (size_t)oc * SVOX + (size_t)d * HW + h * W_DIM + wx, acc[m][r]);
        }
    }
}

// ---------------------------------------------------------------------------
// Direct 3x3x3 conv (round-3 proven) — used for head (C_in=1) and tail (C_out=6).
// ---------------------------------------------------------------------------
template <typename Tin, typename Tout, int BC>
__global__ __launch_bounds__(256) void conv3d_k(const Tin* __restrict__ x,
                                                const float* __restrict__ w,
                                                Tout* __restrict__ out,
                                                int C_in, int C_out_w, int Ch, int c0,
                                                int deconv) {
    __shared__ float tile[3 * 18 * 18];
    __shared__ float wsh[BC * 27];

    const int t = threadIdx.x;
    const int lx = t & 15;
    const int ly = t >> 4;
    const int tx0 = (blockIdx.x % 6) * 16;
    const int ty0 = (blockIdx.x / 6) * 16;
    const int d = blockIdx.y;
    const int gidx = blockIdx.z;
    const int ocw0 = gidx * Ch + c0;
    const int oco0 = gidx * BC;

    float acc[BC];
#pragma unroll
    for (int i = 0; i < BC; ++i) acc[i] = 0.0f;

    for (int ci = 0; ci < C_in; ++ci) {
        __syncthreads();
        for (int i = t; i < BC * 27; i += 256) {
            int o = i / 27, k = i % 27;
            int oc = ocw0 + o;
            wsh[i] = deconv ? w[((size_t)ci * C_out_w + oc) * 27 + (26 - k)]
                            : w[((size_t)oc * C_in + ci) * 27 + k];
        }
        const Tin* xc = x + (size_t)ci * SVOX;
        for (int i = t; i < 3 * 18 * 18; i += 256) {
            int dz = i / 324;
            int rem = i % 324;
            int r = rem / 18;
            int cc = rem % 18;
            int gd = d + dz - 1;
            int gy = ty0 + r - 1;
            int gx = tx0 + cc - 1;
            float v = 0.0f;
            if ((unsigned)gd < D_DIM && (unsigned)gy < H_DIM && (unsigned)gx < W_DIM)
                v = ldf(xc + ((size_t)gd * H_DIM + gy) * W_DIM + gx);
            tile[i] = v;
        }
        __syncthreads();
#pragma unroll
        for (int kd = 0; kd < 3; ++kd)
#pragma unroll
            for (int kh = 0; kh < 3; ++kh)
#pragma unroll
                for (int kw = 0; kw < 3; ++kw) {
                    float v = tile[kd * 324 + (ly + kh) * 18 + (lx + kw)];
                    const int k = (kd * 3 + kh) * 3 + kw;
#pragma unroll
                    for (int o = 0; o < BC; ++o)
                        acc[o] = fmaf(v, wsh[o * 27 + k], acc[o]);
                }
    }

    const int hy = ty0 + ly, wx = tx0 + lx;
#pragma unroll
    for (int o = 0; o < BC; ++o)
        stf(out + (size_t)(oco0 + o) * SVOX + (size_t)d * HW + hy * W_DIM + wx, acc[o]);
}

// ---------------------------------------------------------------------------
// SRU scans (unchanged from round-3 PASS).
// ---------------------------------------------------------------------------
template <typename Tg, typename Tio>
__global__ __launch_bounds__(256) void do_sru_scan_k(const Tg* __restrict__ g,
                                                     const Tio* __restrict__ resid,
                                                     Tio* __restrict__ out,
                                                     int chunk, int c0) {
    int idx = blockIdx.x * blockDim.x + threadIdx.x;
    if (idx >= chunk * HW) return;
    int c = idx / HW, hw = idx % HW;
    const size_t gbase = (size_t)c * SVOX + hw;
    const size_t gs = (size_t)chunk * SVOX;
    const size_t obase = (size_t)(c0 + c) * SVOX + hw;
    const Tg* gW = g + gbase;
    const Tg* gF = g + gs + gbase;
    const Tg* gF2 = g + 2 * gs + gbase;
    const Tg* gR = g + 3 * gs + gbase;
    const Tg* gR2 = g + 4 * gs + gbase;
    const Tg* gX = g + 5 * gs + gbase;

    float hbuf[D_DIM];
    float C = 0.0f;
#pragma unroll
    for (int d = 0; d < D_DIM; ++d) {
        float f = sigm(ldf(gF + d * HW));
        float r = sigm(ldf(gR + d * HW));
        float xv = tanhf(ldf(gX + d * HW));
        float wv = tanhf(ldf(gW + d * HW));
        C = (d == 0) ? (1.0f - f) : (f * C + (1.0f - f) * wv);
        hbuf[d] = r * C + (1.0f - r) * xv;
    }
#pragma unroll
    for (int i = 0; i < D_DIM; ++i) {
        int d = D_DIM - 1 - i;
        float f = sigm(ldf(gF2 + d * HW));
        float r = sigm(ldf(gR2 + d * HW));
        float xv = tanhf(ldf(gX + d * HW));
        float wv = tanhf(ldf(gW + d * HW));
        C = (i == 0) ? (1.0f - f) : (f * C + (1.0f - f) * wv);
        float hv = r * C + (1.0f - r) * xv;
        float res = resid ? ldf(resid + obase + d * HW) : 0.0f;
        hbuf[d] += hv + res;
    }
#pragma unroll
    for (int d = 0; d < D_DIM; ++d) stf(out + obase + d * HW, hbuf[d]);
}

template <typename T, int REV>
__global__ __launch_bounds__(256) void si_sru_scan_k(const T* __restrict__ g,
                                                     const T* __restrict__ resid,
                                                     T* __restrict__ out,
                                                     int chunk, int c0) {
    int idx = blockIdx.x * blockDim.x + threadIdx.x;
    if (idx >= chunk * HW) return;
    int c = idx / HW, hw = idx % HW;
    const size_t gbase = (size_t)c * SVOX + hw;
    const size_t gs = (size_t)chunk * SVOX;
    const size_t obase = (size_t)(c0 + c) * SVOX + hw;
    const T* gW = g + gbase;
    const T* gF = g + gs + gbase;
    const T* gR = g + 2 * gs + gbase;
    const T* gX = g + 3 * gs + gbase;

    float C = 0.0f;
#pragma unroll
    for (int i = 0; i < D_DIM; ++i) {
        int d = REV ? (D_DIM - 1 - i) : i;
        float f = sigm(ldf(gF + d * HW));
        float r = sigm(ldf(gR + d * HW));
        float xv = tanhf(ldf(gX + d * HW));
        float wv = tanhf(ldf(gW + d * HW));
        C = (i == 0) ? (1.0f - f) : (f * C + (1.0f - f) * wv);
        float hv = r * C + (1.0f - r) * xv;
        float o = hv + (resid ? ldf(resid + obase + d * HW) : 0.0f);
        stf(out + obase + d * HW, o);
    }
}

// ---------------------------------------------------------------------------
extern "C" void kernel_launch(void* const* d_in, const int* in_sizes, int n_in,
                              void* d_out, int out_size, void* d_ws, size_t ws_size,
                              hipStream_t stream) {
    const float* x      = (const float*)d_in[0];
    const float* w_head = (const float*)d_in[1];  // (96, 1, 27)
    const float* w_e0   = (const float*)d_in[2];  // (128, 16, 27)
    const float* w_e1   = (const float*)d_in[3];  // (256, 32, 27)
    const float* w_d0   = (const float*)d_in[4];  // (64, 128, 27)  deconv
    const float* w_d1   = (const float*)d_in[5];  // (32, 64, 27)   deconv
    const float* w_tail = (const float*)d_in[6];  // (16, 6, 27)    deconv
    float* out = (float*)d_out;

    bf16* g  = (bf16*)d_ws;               // 48*S (si convs use first 32*S)
    bf16* wt = g + (size_t)32 * SVOX;     // transformed weights (<=432 KB) in spare 16*S
    bf16* H  = g + (size_t)48 * SVOX;     // 16*S
    bf16* E0 = H + (size_t)16 * SVOX;     // 32*S (d0 in-place)
    bf16* E1 = E0 + (size_t)32 * SVOX;    // 64*S (d1 over dead e1)
    bf16* D0 = E0;
    bf16* D1 = E1;

    dim3 blk(256);
    const dim3 sg8(8 * 36);         // scan grid: 8*HW/256
    const dim3 mg(H_DIM, D_DIM);    // mfma conv grid: (h, d)

    // 1. head: direct conv 1->96 (Ch=16, 6 groups), do_sru -> H
    for (int c0 = 0; c0 < 16; c0 += 8) {
        conv3d_k<float, bf16, 8><<<dim3(36, 31, 6), blk, 0, stream>>>(x, w_head, g, 1, 96, 16, c0, 0);
        do_sru_scan_k<bf16, bf16><<<sg8, blk, 0, stream>>>(g, (const bf16*)nullptr, H, 8, c0);
    }
    // 2. e0: mfma conv 16->128 (Ch=32, 4 chunks, KB=1), si_sru fwd -> E0
    {
        const int cip = 32, nch = 4, csz = 27 * 32 * cip;
        wtrans_k<<<dim3((nch * csz + 255) / 256), blk, 0, stream>>>(w_e0, wt, 16, 128, 32, 0, cip, nch * csz);
        for (int c = 0; c < nch; ++c) {
            conv_mfma_k<1><<<mg, blk, 0, stream>>>(H, wt + (size_t)c * csz, g, 16);
            si_sru_scan_k<bf16, 0><<<sg8, blk, 0, stream>>>(g, (const bf16*)nullptr, E0, 8, c * 8);
        }
    }
    // 3. e1: mfma conv 32->256 (Ch=64, 8 chunks, KB=1), si_sru rev -> E1
    {
        const int cip = 32, nch = 8, csz = 27 * 32 * cip;
        wtrans_k<<<dim3((nch * csz + 255) / 256), blk, 0, stream>>>(w_e1, wt, 32, 256, 64, 0, cip, nch * csz);
        for (int c = 0; c < nch; ++c) {
            conv_mfma_k<1><<<mg, blk, 0, stream>>>(E0, wt + (size_t)c * csz, g, 32);
            si_sru_scan_k<bf16, 1><<<sg8, blk, 0, stream>>>(g, (const bf16*)nullptr, E1, 8, c * 8);
        }
    }
    // 4. d0: mfma deconv 64->128 (Ch=32, 4 chunks, KB=2), si_sru fwd + e0 -> D0
    {
        const int cip = 64, nch = 4, csz = 27 * 32 * cip;
        wtrans_k<<<dim3((nch * csz + 255) / 256), blk, 0, stream>>>(w_d0, wt, 64, 128, 32, 1, cip, nch * csz);
        for (int c = 0; c < nch; ++c) {
            conv_mfma_k<2><<<mg, blk, 0, stream>>>(E1, wt + (size_t)c * csz, g, 64);
            si_sru_scan_k<bf16, 0><<<sg8, blk, 0, stream>>>(g, E0, D0, 8, c * 8);
        }
    }
    // 5. d1: mfma deconv 32->64 (Ch=16, 2 chunks, KB=1), si_sru rev + h -> D1
    {
        const int cip = 32, nch = 2, csz = 27 * 32 * cip;
        wtrans_k<<<dim3((nch * csz + 255) / 256), blk, 0, stream>>>(w_d1, wt, 32, 64, 16, 1, cip, nch * csz);
        for (int c = 0; c < nch; ++c) {
            conv_mfma_k<1><<<mg, blk, 0, stream>>>(D0, wt + (size_t)c * csz, g, 32);
            si_sru_scan_k<bf16, 1><<<sg8, blk, 0, stream>>>(g, H, D1, 8, c * 8);
        }
    }
    // 6. tail: direct deconv 16->6 (Ch=1, 6 groups), do_sru + x -> out (fp32)
    conv3d_k<bf16, bf16, 1><<<dim3(36, 31, 6), blk, 0, stream>>>(D1, w_tail, g, 16, 6, 1, 0, 1);
    do_sru_scan_k<bf16, float><<<dim3(36), blk, 0, stream>>>(g, x, out, 1, 0);
}

// Round 6
// 1638.997 us; speedup vs baseline: 12.8875x; 2.0436x over previous
//
#include <hip/hip_runtime.h>
#include <hip/hip_bf16.h>

// NSSNN forward on MI355X. x (1,1,31,96,96) fp32. S = 31*96*96 = 285696.
// Round-6: MFMA implicit-GEMM conv v2 — d-slab staging. Block = (d, 4 h-rows)
// x 32 compact oc. Per (kd, ci-chunk): stage 6 rows x 98 w x 32 ci slab once
// in LDS (b128 writes, 2-way-free bank pattern), serving all 9 (kh,kw) taps.
// Head/tail direct conv + SRU scans unchanged from round-5 PASS.
// Workspace (bf16): g(48*S) | h(16*S) | e0(32*S) | e1(64*S) = 91.4 MB;
// wt (transformed weights, <=442KB) in g+32S..48S.

#define D_DIM 31
#define H_DIM 96
#define W_DIM 96
#define HW (H_DIM * W_DIM)
#define SVOX (D_DIM * HW)

typedef __hip_bfloat16 bf16;
typedef __attribute__((ext_vector_type(8))) short short8;
typedef __attribute__((ext_vector_type(4))) float f32x4;

__device__ __forceinline__ float sigm(float v) { return 1.0f / (1.0f + __expf(-v)); }

template <typename T> __device__ __forceinline__ float ldf(const T* p);
template <> __device__ __forceinline__ float ldf<float>(const float* p) { return *p; }
template <> __device__ __forceinline__ float ldf<bf16>(const bf16* p) {
    return __bfloat162float(*p);
}
template <typename T> __device__ __forceinline__ void stf(T* p, float v);
template <> __device__ __forceinline__ void stf<float>(float* p, float v) { *p = v; }
template <> __device__ __forceinline__ void stf<bf16>(bf16* p, float v) {
    *p = __float2bfloat16(v);
}

// ---------------------------------------------------------------------------
// Weight transform: wt[chunk][kk][oc_c(32)][ci(cip)] bf16, zero-padded ci>=C_in.
// oc_w = (oc_c>>3)*Ch + chunk*8 + (oc_c&7).
// normal: w (C_out_w, C_in, 27);  deconv: w (C_in, C_out_w, 27) + spatial flip.
// ---------------------------------------------------------------------------
__global__ __launch_bounds__(256) void wtrans_k(const float* __restrict__ w,
                                                bf16* __restrict__ wt,
                                                int C_in, int C_out_w, int Ch,
                                                int deconv, int cip, int total) {
    int i = blockIdx.x * 256 + threadIdx.x;
    if (i >= total) return;
    int ci = i % cip;
    int r = i / cip;
    int oc_c = r & 31; r >>= 5;
    int kk = r % 27;
    int chunk = r / 27;
    int oc_w = (oc_c >> 3) * Ch + chunk * 8 + (oc_c & 7);
    float v = 0.0f;
    if (ci < C_in)
        v = deconv ? w[((size_t)ci * C_out_w + oc_w) * 27 + (26 - kk)]
                   : w[((size_t)oc_w * C_in + ci) * 27 + kk];
    wt[i] = __float2bfloat16(v);
}

// ---------------------------------------------------------------------------
// MFMA implicit-GEMM conv v2. Grid (24, 31): block = rows h0..h0+3 at depth d,
// 32 compact oc. 4 waves: nt = wave>>1 (16-oc tile), half = wave&1 (2 rows).
// Per (kd, cb): stage slab [hl 6][wp 98][ci 32 pad40] (b128 writes, lane
// stride 80B), then 9 taps x 12 M-tiles/wave of mfma_f32_16x16x32_bf16.
// A: lane&15=oc, (lane>>4)*8=ci slice.  B: lane&15=w, (lane>>4)*8=ci slice.
// D: oc=(lane>>4)*4+reg, w=lane&15   [harness-verified in round 5].
// ---------------------------------------------------------------------------
template <int CI32>
__global__ __launch_bounds__(256) void conv_mfma_k(const bf16* __restrict__ x,
                                                   const bf16* __restrict__ wt,
                                                   bf16* __restrict__ out, int C_in) {
    constexpr int RS = 40;                 // ci slot: 32 + 8 pad (80 B, 16B-aligned)
    __shared__ short row[6 * 98 * RS];     // 47 KB

    const int t = threadIdx.x;
    const int lane = t & 63, wave = t >> 6;
    const int l15 = lane & 15, g4 = lane >> 4;
    const int h0 = blockIdx.x * 4, d = blockIdx.y;
    const int nt = wave >> 1;              // oc tile (16)
    const int half = wave & 1;             // rows half*2, half*2+1
    const short* xs = (const short*)x;

    f32x4 acc[12];
#pragma unroll
    for (int m = 0; m < 12; ++m) acc[m] = (f32x4){0.f, 0.f, 0.f, 0.f};

    for (int kd = 0; kd < 3; ++kd) {
        const int dd = d + kd - 1;
        if ((unsigned)dd >= D_DIM) continue;  // block-uniform -> barriers stay uniform
        for (int cb = 0; cb < CI32; ++cb) {
            __syncthreads();  // protect LDS from previous stage's readers
            // stage slab: items (wp 98, hl 6, cg 4) = 2352; 8 loads + 1 b128 write
            for (int i = t; i < 98 * 6 * 4; i += 256) {
                int wp = i % 98;
                int j = i / 98;
                int hl = j % 6;
                int cg = j / 6;
                int hh = h0 + hl - 1;
                int gw = wp - 1;
                short8 v = {0, 0, 0, 0, 0, 0, 0, 0};
                const int cib = cb * 32 + cg * 8;
                if ((unsigned)hh < H_DIM && (unsigned)gw < W_DIM && cib < C_in) {
                    const short* xp = xs + (size_t)cib * SVOX + (size_t)dd * HW + hh * W_DIM + gw;
#pragma unroll
                    for (int u = 0; u < 8; ++u) v[u] = xp[(size_t)u * SVOX];
                }
                *(short8*)(row + ((size_t)hl * 98 + wp) * RS + cg * 8) = v;
            }
            __syncthreads();

            const bf16* wa = wt + (size_t)(nt * 16 + l15) * (CI32 * 32) + cb * 32 + g4 * 8;
#pragma unroll
            for (int kh = 0; kh < 3; ++kh) {
#pragma unroll
                for (int kw = 0; kw < 3; ++kw) {
                    const int kk = (kd * 3 + kh) * 3 + kw;
                    short8 a = *(const short8*)(wa + (size_t)kk * 32 * (CI32 * 32));
                    const int boff = ((kh * 98) + l15 + kw) * RS + g4 * 8;
#pragma unroll
                    for (int m = 0; m < 12; ++m) {
                        const int r = half * 2 + (m >> 2) - half * 2 + (m / 6);  // see below
                        // m -> (row in 0..1, wtile in 0..5)
                        const int rr = m / 6, wt6 = m % 6;
                        short8 b = *(const short8*)(row + boff +
                                                    ((half * 2 + rr) * 98 + wt6 * 16) * RS);
                        acc[m] = __builtin_amdgcn_mfma_f32_16x16x32_bf16(a, b, acc[m], 0, 0, 0);
                        (void)r;
                    }
                }
            }
        }
    }

    // C-write: h = h0 + half*2 + rr, w = wt6*16 + l15, oc = nt*16 + g4*4 + reg
#pragma unroll
    for (int m = 0; m < 12; ++m) {
        const int rr = m / 6, wt6 = m % 6;
        const int hy = h0 + half * 2 + rr;
        const int wx = wt6 * 16 + l15;
#pragma unroll
        for (int r = 0; r < 4; ++r) {
            const int oc = nt * 16 + g4 * 4 + r;
            stf(out + (size_t)oc * SVOX + (size_t)d * HW + hy * W_DIM + wx, acc[m][r]);
        }
    }
}

// ---------------------------------------------------------------------------
// Direct 3x3x3 conv (round-3 proven) — head (C_in=1) and tail (C_out=6).
// ---------------------------------------------------------------------------
template <typename Tin, typename Tout, int BC>
__global__ __launch_bounds__(256) void conv3d_k(const Tin* __restrict__ x,
                                                const float* __restrict__ w,
                                                Tout* __restrict__ out,
                                                int C_in, int C_out_w, int Ch, int c0,
                                                int deconv) {
    __shared__ float tile[3 * 18 * 18];
    __shared__ float wsh[BC * 27];

    const int t = threadIdx.x;
    const int lx = t & 15;
    const int ly = t >> 4;
    const int tx0 = (blockIdx.x % 6) * 16;
    const int ty0 = (blockIdx.x / 6) * 16;
    const int d = blockIdx.y;
    const int gidx = blockIdx.z;
    const int ocw0 = gidx * Ch + c0;
    const int oco0 = gidx * BC;

    float acc[BC];
#pragma unroll
    for (int i = 0; i < BC; ++i) acc[i] = 0.0f;

    for (int ci = 0; ci < C_in; ++ci) {
        __syncthreads();
        for (int i = t; i < BC * 27; i += 256) {
            int o = i / 27, k = i % 27;
            int oc = ocw0 + o;
            wsh[i] = deconv ? w[((size_t)ci * C_out_w + oc) * 27 + (26 - k)]
                            : w[((size_t)oc * C_in + ci) * 27 + k];
        }
        const Tin* xc = x + (size_t)ci * SVOX;
        for (int i = t; i < 3 * 18 * 18; i += 256) {
            int dz = i / 324;
            int rem = i % 324;
            int r = rem / 18;
            int cc = rem % 18;
            int gd = d + dz - 1;
            int gy = ty0 + r - 1;
            int gx = tx0 + cc - 1;
            float v = 0.0f;
            if ((unsigned)gd < D_DIM && (unsigned)gy < H_DIM && (unsigned)gx < W_DIM)
                v = ldf(xc + ((size_t)gd * H_DIM + gy) * W_DIM + gx);
            tile[i] = v;
        }
        __syncthreads();
#pragma unroll
        for (int kd = 0; kd < 3; ++kd)
#pragma unroll
            for (int kh = 0; kh < 3; ++kh)
#pragma unroll
                for (int kw = 0; kw < 3; ++kw) {
                    float v = tile[kd * 324 + (ly + kh) * 18 + (lx + kw)];
                    const int k = (kd * 3 + kh) * 3 + kw;
#pragma unroll
                    for (int o = 0; o < BC; ++o)
                        acc[o] = fmaf(v, wsh[o * 27 + k], acc[o]);
                }
    }

    const int hy = ty0 + ly, wx = tx0 + lx;
#pragma unroll
    for (int o = 0; o < BC; ++o)
        stf(out + (size_t)(oco0 + o) * SVOX + (size_t)d * HW + hy * W_DIM + wx, acc[o]);
}

// ---------------------------------------------------------------------------
// SRU scans (unchanged from round-3 PASS).
// ---------------------------------------------------------------------------
template <typename Tg, typename Tio>
__global__ __launch_bounds__(256) void do_sru_scan_k(const Tg* __restrict__ g,
                                                     const Tio* __restrict__ resid,
                                                     Tio* __restrict__ out,
                                                     int chunk, int c0) {
    int idx = blockIdx.x * blockDim.x + threadIdx.x;
    if (idx >= chunk * HW) return;
    int c = idx / HW, hw = idx % HW;
    const size_t gbase = (size_t)c * SVOX + hw;
    const size_t gs = (size_t)chunk * SVOX;
    const size_t obase = (size_t)(c0 + c) * SVOX + hw;
    const Tg* gW = g + gbase;
    const Tg* gF = g + gs + gbase;
    const Tg* gF2 = g + 2 * gs + gbase;
    const Tg* gR = g + 3 * gs + gbase;
    const Tg* gR2 = g + 4 * gs + gbase;
    const Tg* gX = g + 5 * gs + gbase;

    float hbuf[D_DIM];
    float C = 0.0f;
#pragma unroll
    for (int d = 0; d < D_DIM; ++d) {
        float f = sigm(ldf(gF + d * HW));
        float r = sigm(ldf(gR + d * HW));
        float xv = tanhf(ldf(gX + d * HW));
        float wv = tanhf(ldf(gW + d * HW));
        C = (d == 0) ? (1.0f - f) : (f * C + (1.0f - f) * wv);
        hbuf[d] = r * C + (1.0f - r) * xv;
    }
#pragma unroll
    for (int i = 0; i < D_DIM; ++i) {
        int d = D_DIM - 1 - i;
        float f = sigm(ldf(gF2 + d * HW));
        float r = sigm(ldf(gR2 + d * HW));
        float xv = tanhf(ldf(gX + d * HW));
        float wv = tanhf(ldf(gW + d * HW));
        C = (i == 0) ? (1.0f - f) : (f * C + (1.0f - f) * wv);
        float hv = r * C + (1.0f - r) * xv;
        float res = resid ? ldf(resid + obase + d * HW) : 0.0f;
        hbuf[d] += hv + res;
    }
#pragma unroll
    for (int d = 0; d < D_DIM; ++d) stf(out + obase + d * HW, hbuf[d]);
}

template <typename T, int REV>
__global__ __launch_bounds__(256) void si_sru_scan_k(const T* __restrict__ g,
                                                     const T* __restrict__ resid,
                                                     T* __restrict__ out,
                                                     int chunk, int c0) {
    int idx = blockIdx.x * blockDim.x + threadIdx.x;
    if (idx >= chunk * HW) return;
    int c = idx / HW, hw = idx % HW;
    const size_t gbase = (size_t)c * SVOX + hw;
    const size_t gs = (size_t)chunk * SVOX;
    const size_t obase = (size_t)(c0 + c) * SVOX + hw;
    const T* gW = g + gbase;
    const T* gF = g + gs + gbase;
    const T* gR = g + 2 * gs + gbase;
    const T* gX = g + 3 * gs + gbase;

    float C = 0.0f;
#pragma unroll
    for (int i = 0; i < D_DIM; ++i) {
        int d = REV ? (D_DIM - 1 - i) : i;
        float f = sigm(ldf(gF + d * HW));
        float r = sigm(ldf(gR + d * HW));
        float xv = tanhf(ldf(gX + d * HW));
        float wv = tanhf(ldf(gW + d * HW));
        C = (i == 0) ? (1.0f - f) : (f * C + (1.0f - f) * wv);
        float hv = r * C + (1.0f - r) * xv;
        float o = hv + (resid ? ldf(resid + obase + d * HW) : 0.0f);
        stf(out + obase + d * HW, o);
    }
}

// ---------------------------------------------------------------------------
extern "C" void kernel_launch(void* const* d_in, const int* in_sizes, int n_in,
                              void* d_out, int out_size, void* d_ws, size_t ws_size,
                              hipStream_t stream) {
    const float* x      = (const float*)d_in[0];
    const float* w_head = (const float*)d_in[1];  // (96, 1, 27)
    const float* w_e0   = (const float*)d_in[2];  // (128, 16, 27)
    const float* w_e1   = (const float*)d_in[3];  // (256, 32, 27)
    const float* w_d0   = (const float*)d_in[4];  // (64, 128, 27)  deconv
    const float* w_d1   = (const float*)d_in[5];  // (32, 64, 27)   deconv
    const float* w_tail = (const float*)d_in[6];  // (16, 6, 27)    deconv
    float* out = (float*)d_out;

    bf16* g  = (bf16*)d_ws;               // 48*S (si convs use first 32*S)
    bf16* wt = g + (size_t)32 * SVOX;     // transformed weights in spare 16*S
    bf16* H  = g + (size_t)48 * SVOX;     // 16*S
    bf16* E0 = H + (size_t)16 * SVOX;     // 32*S (d0 in-place)
    bf16* E1 = E0 + (size_t)32 * SVOX;    // 64*S (d1 over dead e1)
    bf16* D0 = E0;
    bf16* D1 = E1;

    dim3 blk(256);
    const dim3 sg8(8 * 36);            // scan grid: 8*HW/256
    const dim3 mg(H_DIM / 4, D_DIM);   // mfma conv grid: (24 h-slabs, d)

    // 1. head: direct conv 1->96 (Ch=16, 6 groups), do_sru -> H
    for (int c0 = 0; c0 < 16; c0 += 8) {
        conv3d_k<float, bf16, 8><<<dim3(36, 31, 6), blk, 0, stream>>>(x, w_head, g, 1, 96, 16, c0, 0);
        do_sru_scan_k<bf16, bf16><<<sg8, blk, 0, stream>>>(g, (const bf16*)nullptr, H, 8, c0);
    }
    // 2. e0: mfma conv 16->128 (Ch=32, 4 chunks, CI32=1), si_sru fwd -> E0
    {
        const int cip = 32, nch = 4, csz = 27 * 32 * cip;
        wtrans_k<<<dim3((nch * csz + 255) / 256), blk, 0, stream>>>(w_e0, wt, 16, 128, 32, 0, cip, nch * csz);
        for (int c = 0; c < nch; ++c) {
            conv_mfma_k<1><<<mg, blk, 0, stream>>>(H, wt + (size_t)c * csz, g, 16);
            si_sru_scan_k<bf16, 0><<<sg8, blk, 0, stream>>>(g, (const bf16*)nullptr, E0, 8, c * 8);
        }
    }
    // 3. e1: mfma conv 32->256 (Ch=64, 8 chunks, CI32=1), si_sru rev -> E1
    {
        const int cip = 32, nch = 8, csz = 27 * 32 * cip;
        wtrans_k<<<dim3((nch * csz + 255) / 256), blk, 0, stream>>>(w_e1, wt, 32, 256, 64, 0, cip, nch * csz);
        for (int c = 0; c < nch; ++c) {
            conv_mfma_k<1><<<mg, blk, 0, stream>>>(E0, wt + (size_t)c * csz, g, 32);
            si_sru_scan_k<bf16, 1><<<sg8, blk, 0, stream>>>(g, (const bf16*)nullptr, E1, 8, c * 8);
        }
    }
    // 4. d0: mfma deconv 64->128 (Ch=32, 4 chunks, CI32=2), si_sru fwd + e0 -> D0
    {
        const int cip = 64, nch = 4, csz = 27 * 32 * cip;
        wtrans_k<<<dim3((nch * csz + 255) / 256), blk, 0, stream>>>(w_d0, wt, 64, 128, 32, 1, cip, nch * csz);
        for (int c = 0; c < nch; ++c) {
            conv_mfma_k<2><<<mg, blk, 0, stream>>>(E1, wt + (size_t)c * csz, g, 64);
            si_sru_scan_k<bf16, 0><<<sg8, blk, 0, stream>>>(g, E0, D0, 8, c * 8);
        }
    }
    // 5. d1: mfma deconv 32->64 (Ch=16, 2 chunks, CI32=1), si_sru rev + h -> D1
    {
        const int cip = 32, nch = 2, csz = 27 * 32 * cip;
        wtrans_k<<<dim3((nch * csz + 255) / 256), blk, 0, stream>>>(w_d1, wt, 32, 64, 16, 1, cip, nch * csz);
        for (int c = 0; c < nch; ++c) {
            conv_mfma_k<1><<<mg, blk, 0, stream>>>(D0, wt + (size_t)c * csz, g, 32);
            si_sru_scan_k<bf16, 1><<<sg8, blk, 0, stream>>>(g, H, D1, 8, c * 8);
        }
    }
    // 6. tail: direct deconv 16->6 (Ch=1, 6 groups), do_sru + x -> out (fp32)
    conv3d_k<bf16, bf16, 1><<<dim3(36, 31, 6), blk, 0, stream>>>(D1, w_tail, g, 16, 6, 1, 0, 1);
    do_sru_scan_k<bf16, float><<<dim3(36), blk, 0, stream>>>(g, x, out, 1, 0);
}

// Round 7
// 1636.388 us; speedup vs baseline: 12.9080x; 1.0016x over previous
//
#include <hip/hip_runtime.h>
#include <hip/hip_bf16.h>

// NSSNN forward on MI355X. x (1,1,31,96,96) fp32. S = 31*96*96 = 285696.
// Round-7: (a) conv_mfma v3 — per-wave B-reuse across both oc-tiles
// (12 MFMA per 6 B-loads, 32 FLOP/LDS-byte); (b) direct-conv v2 with 2x2
// microtile for head/tail (4x weight-read amortization); (c) merged wtrans.
// Workspace (bf16): g(48*S) | H(16*S) | E0(32*S) | E1(64*S) = 91.4 MB;
// wt (all 4 layers, 0.61M elems) at g+32S, written after head completes.

#define D_DIM 31
#define H_DIM 96
#define W_DIM 96
#define HW (H_DIM * W_DIM)
#define SVOX (D_DIM * HW)

typedef __hip_bfloat16 bf16;
typedef __attribute__((ext_vector_type(8))) short short8;
typedef __attribute__((ext_vector_type(4))) float f32x4;

__device__ __forceinline__ float sigm(float v) { return 1.0f / (1.0f + __expf(-v)); }

template <typename T> __device__ __forceinline__ float ldf(const T* p);
template <> __device__ __forceinline__ float ldf<float>(const float* p) { return *p; }
template <> __device__ __forceinline__ float ldf<bf16>(const bf16* p) {
    return __bfloat162float(*p);
}
template <typename T> __device__ __forceinline__ void stf(T* p, float v);
template <> __device__ __forceinline__ void stf<float>(float* p, float v) { *p = v; }
template <> __device__ __forceinline__ void stf<bf16>(bf16* p, float v) {
    *p = __float2bfloat16(v);
}

// ---------------------------------------------------------------------------
// Merged weight transform, all 4 MFMA layers into one wt arena:
//   wt[region][chunk][kk][oc_c(32)][ci(cip)] bf16, zero-padded ci>=C_in.
// oc_w = (oc_c>>3)*Ch + chunk*8 + (oc_c&7).
// Regions (elems): e0 [0,110592) e1 [110592,331776) d0 [331776,552960)
//                  d1 [552960,608256)
// ---------------------------------------------------------------------------
__global__ __launch_bounds__(256) void wtrans_all_k(const float* __restrict__ w_e0,
                                                    const float* __restrict__ w_e1,
                                                    const float* __restrict__ w_d0,
                                                    const float* __restrict__ w_d1,
                                                    bf16* __restrict__ wt) {
    int i = blockIdx.x * 256 + threadIdx.x;
    if (i >= 608256) return;
    const float* w;
    int j, C_in, C_out_w, Ch, deconv, cip;
    if (i < 110592)      { w = w_e0; j = i;          C_in = 16; C_out_w = 128; Ch = 32; deconv = 0; cip = 32; }
    else if (i < 331776) { w = w_e1; j = i - 110592; C_in = 32; C_out_w = 256; Ch = 64; deconv = 0; cip = 32; }
    else if (i < 552960) { w = w_d0; j = i - 331776; C_in = 64; C_out_w = 128; Ch = 32; deconv = 1; cip = 64; }
    else                 { w = w_d1; j = i - 552960; C_in = 32; C_out_w = 64;  Ch = 16; deconv = 1; cip = 32; }
    int ci = j % cip;
    int r = j / cip;
    int oc_c = r & 31; r >>= 5;
    int kk = r % 27;
    int chunk = r / 27;
    int oc_w = (oc_c >> 3) * Ch + chunk * 8 + (oc_c & 7);
    float v = 0.0f;
    if (ci < C_in)
        v = deconv ? w[((size_t)ci * C_out_w + oc_w) * 27 + (26 - kk)]
                   : w[((size_t)oc_w * C_in + ci) * 27 + kk];
    wt[i] = __float2bfloat16(v);
}

// ---------------------------------------------------------------------------
// MFMA implicit-GEMM conv v3. Grid (24, 31): block = 4 h-rows at depth d,
// 32 compact oc. 4 waves: wave = h-row. Per wave per tap: 6 B-loads (LDS) +
// 2 A-loads (wt, L2) -> 12 mfma_f32_16x16x32_bf16 (B reused across both
// oc-tiles -> 32 FLOP per LDS byte). Slab [6 rows][98 w][32 ci pad40].
// D: oc = nt*16 + (lane>>4)*4 + reg, w = lane&15  [harness-verified r5/r6].
// ---------------------------------------------------------------------------
template <int CI32>
__global__ __launch_bounds__(256) void conv_mfma_k(const bf16* __restrict__ x,
                                                   const bf16* __restrict__ wt,
                                                   bf16* __restrict__ out, int C_in) {
    constexpr int RS = 40;              // ci slot: 32 + 8 pad (80 B, 16B-aligned)
    constexpr int CIP = CI32 * 32;      // wt ci stride
    __shared__ short row[6 * 98 * RS];  // 47,040 B -> 3 blocks/CU

    const int t = threadIdx.x;
    const int lane = t & 63, wave = t >> 6;
    const int l15 = lane & 15, g4 = lane >> 4;
    const int h0 = blockIdx.x * 4, d = blockIdx.y;
    const short* xs = (const short*)x;

    f32x4 acc[6][2];
#pragma unroll
    for (int m = 0; m < 6; ++m)
#pragma unroll
        for (int n = 0; n < 2; ++n) acc[m][n] = (f32x4){0.f, 0.f, 0.f, 0.f};

    for (int kd = 0; kd < 3; ++kd) {
        const int dd = d + kd - 1;
        if ((unsigned)dd >= D_DIM) continue;  // block-uniform
        for (int cb = 0; cb < CI32; ++cb) {
            __syncthreads();
            // stage slab: (wp 98, hl 6, cg 4) = 2352 items; 8 loads + 1 b128 write
            for (int i = t; i < 98 * 6 * 4; i += 256) {
                int wp = i % 98;
                int j = i / 98;
                int hl = j % 6;
                int cg = j / 6;
                int hh = h0 + hl - 1;
                int gw = wp - 1;
                short8 v = {0, 0, 0, 0, 0, 0, 0, 0};
                const int cib = cb * 32 + cg * 8;
                if ((unsigned)hh < H_DIM && (unsigned)gw < W_DIM && cib < C_in) {
                    const short* xp = xs + (size_t)cib * SVOX + (size_t)dd * HW + hh * W_DIM + gw;
#pragma unroll
                    for (int u = 0; u < 8; ++u) v[u] = xp[(size_t)u * SVOX];
                }
                *(short8*)(row + ((size_t)hl * 98 + wp) * RS + cg * 8) = v;
            }
            __syncthreads();

            const bf16* wa = wt + (size_t)l15 * CIP + cb * 32 + g4 * 8;
#pragma unroll
            for (int kh = 0; kh < 3; ++kh) {
#pragma unroll
                for (int kw = 0; kw < 3; ++kw) {
                    const int kk = (kd * 3 + kh) * 3 + kw;
                    const size_t arow = (size_t)kk * 32 * CIP;
                    short8 a0 = *(const short8*)(wa + arow);
                    short8 a1 = *(const short8*)(wa + arow + (size_t)16 * CIP);
                    const int boff = ((wave + kh) * 98 + l15 + kw) * RS + g4 * 8;
#pragma unroll
                    for (int m = 0; m < 6; ++m) {
                        short8 b = *(const short8*)(row + boff + (m * 16) * RS);
                        acc[m][0] = __builtin_amdgcn_mfma_f32_16x16x32_bf16(a0, b, acc[m][0], 0, 0, 0);
                        acc[m][1] = __builtin_amdgcn_mfma_f32_16x16x32_bf16(a1, b, acc[m][1], 0, 0, 0);
                    }
                }
            }
        }
    }

    // C-write: h = h0 + wave, w = m*16 + l15, oc = n*16 + g4*4 + reg
    const int hy = h0 + wave;
#pragma unroll
    for (int m = 0; m < 6; ++m) {
        const int wx = m * 16 + l15;
#pragma unroll
        for (int n = 0; n < 2; ++n)
#pragma unroll
            for (int r = 0; r < 4; ++r) {
                const int oc = n * 16 + g4 * 4 + r;
                stf(out + (size_t)oc * SVOX + (size_t)d * HW + hy * W_DIM + wx, acc[m][n][r]);
            }
    }
}

// ---------------------------------------------------------------------------
// Direct conv v2 (head/tail): 32x32 tile (16x16 thr, 2x2 microtile), BC oc of
// one group. Weights staged in LDS per ci, hoisted to regs per (kd,kh) and
// amortized over 4 pixels. oc_w = gidx*Ch + c0 + o; compact = gidx*BC + o.
// ---------------------------------------------------------------------------
template <typename Tin, int BC>
__global__ __launch_bounds__(256) void direct_conv_k(const Tin* __restrict__ x,
                                                     const float* __restrict__ w,
                                                     bf16* __restrict__ out,
                                                     int C_in, int C_out_w, int Ch,
                                                     int c0, int deconv) {
    __shared__ float tile[3][34][36];  // 14.7 KB
    __shared__ float wsh[BC * 27];

    const int t = threadIdx.x;
    const int lx = t & 15;
    const int ly = t >> 4;
    const int tbx = (blockIdx.x % 3) * 32;
    const int tby = (blockIdx.x / 3) * 32;
    const int d = blockIdx.y;
    const int gidx = blockIdx.z;
    const int ocw0 = gidx * Ch + c0;
    const int oco0 = gidx * BC;

    float acc[BC][4];
#pragma unroll
    for (int o = 0; o < BC; ++o)
#pragma unroll
        for (int p = 0; p < 4; ++p) acc[o][p] = 0.0f;

    for (int ci = 0; ci < C_in; ++ci) {
        __syncthreads();
        for (int i = t; i < BC * 27; i += 256) {
            int o = i / 27, k = i % 27;
            int oc = ocw0 + o;
            wsh[i] = deconv ? w[((size_t)ci * C_out_w + oc) * 27 + (26 - k)]
                            : w[((size_t)oc * C_in + ci) * 27 + k];
        }
        const Tin* xc = x + (size_t)ci * SVOX;
        for (int i = t; i < 3 * 34 * 34; i += 256) {
            int dz = i / 1156;
            int rem = i - dz * 1156;
            int r = rem / 34;
            int c = rem - r * 34;
            int gd = d + dz - 1;
            int gy = tby + r - 1;
            int gx = tbx + c - 1;
            float v = 0.0f;
            if ((unsigned)gd < D_DIM && (unsigned)gy < H_DIM && (unsigned)gx < W_DIM)
                v = ldf(xc + ((size_t)gd * H_DIM + gy) * W_DIM + gx);
            tile[dz][r][c] = v;
        }
        __syncthreads();

#pragma unroll
        for (int kd = 0; kd < 3; ++kd)
#pragma unroll
            for (int kh = 0; kh < 3; ++kh) {
                float wv[BC][3];
#pragma unroll
                for (int o = 0; o < BC; ++o)
#pragma unroll
                    for (int kw = 0; kw < 3; ++kw)
                        wv[o][kw] = wsh[o * 27 + (kd * 3 + kh) * 3 + kw];
                const int r0 = ly * 2 + kh;
                float v0[4], v1[4];
#pragma unroll
                for (int c = 0; c < 4; ++c) {
                    v0[c] = tile[kd][r0][lx * 2 + c];
                    v1[c] = tile[kd][r0 + 1][lx * 2 + c];
                }
#pragma unroll
                for (int kw = 0; kw < 3; ++kw)
#pragma unroll
                    for (int o = 0; o < BC; ++o) {
                        acc[o][0] = fmaf(v0[kw],     wv[o][kw], acc[o][0]);
                        acc[o][1] = fmaf(v0[kw + 1], wv[o][kw], acc[o][1]);
                        acc[o][2] = fmaf(v1[kw],     wv[o][kw], acc[o][2]);
                        acc[o][3] = fmaf(v1[kw + 1], wv[o][kw], acc[o][3]);
                    }
            }
    }

    const int hy = tby + ly * 2, wx = tbx + lx * 2;
#pragma unroll
    for (int o = 0; o < BC; ++o) {
        bf16* op = out + (size_t)(oco0 + o) * SVOX + (size_t)d * HW;
        stf(op + (hy + 0) * W_DIM + wx + 0, acc[o][0]);
        stf(op + (hy + 0) * W_DIM + wx + 1, acc[o][1]);
        stf(op + (hy + 1) * W_DIM + wx + 0, acc[o][2]);
        stf(op + (hy + 1) * W_DIM + wx + 1, acc[o][3]);
    }
}

// ---------------------------------------------------------------------------
// SRU scans (unchanged from round-3 PASS).
// ---------------------------------------------------------------------------
template <typename Tg, typename Tio>
__global__ __launch_bounds__(256) void do_sru_scan_k(const Tg* __restrict__ g,
                                                     const Tio* __restrict__ resid,
                                                     Tio* __restrict__ out,
                                                     int chunk, int c0) {
    int idx = blockIdx.x * blockDim.x + threadIdx.x;
    if (idx >= chunk * HW) return;
    int c = idx / HW, hw = idx % HW;
    const size_t gbase = (size_t)c * SVOX + hw;
    const size_t gs = (size_t)chunk * SVOX;
    const size_t obase = (size_t)(c0 + c) * SVOX + hw;
    const Tg* gW = g + gbase;
    const Tg* gF = g + gs + gbase;
    const Tg* gF2 = g + 2 * gs + gbase;
    const Tg* gR = g + 3 * gs + gbase;
    const Tg* gR2 = g + 4 * gs + gbase;
    const Tg* gX = g + 5 * gs + gbase;

    float hbuf[D_DIM];
    float C = 0.0f;
#pragma unroll
    for (int d = 0; d < D_DIM; ++d) {
        float f = sigm(ldf(gF + d * HW));
        float r = sigm(ldf(gR + d * HW));
        float xv = tanhf(ldf(gX + d * HW));
        float wv = tanhf(ldf(gW + d * HW));
        C = (d == 0) ? (1.0f - f) : (f * C + (1.0f - f) * wv);
        hbuf[d] = r * C + (1.0f - r) * xv;
    }
#pragma unroll
    for (int i = 0; i < D_DIM; ++i) {
        int d = D_DIM - 1 - i;
        float f = sigm(ldf(gF2 + d * HW));
        float r = sigm(ldf(gR2 + d * HW));
        float xv = tanhf(ldf(gX + d * HW));
        float wv = tanhf(ldf(gW + d * HW));
        C = (i == 0) ? (1.0f - f) : (f * C + (1.0f - f) * wv);
        float hv = r * C + (1.0f - r) * xv;
        float res = resid ? ldf(resid + obase + d * HW) : 0.0f;
        hbuf[d] += hv + res;
    }
#pragma unroll
    for (int d = 0; d < D_DIM; ++d) stf(out + obase + d * HW, hbuf[d]);
}

template <typename T, int REV>
__global__ __launch_bounds__(256) void si_sru_scan_k(const T* __restrict__ g,
                                                     const T* __restrict__ resid,
                                                     T* __restrict__ out,
                                                     int chunk, int c0) {
    int idx = blockIdx.x * blockDim.x + threadIdx.x;
    if (idx >= chunk * HW) return;
    int c = idx / HW, hw = idx % HW;
    const size_t gbase = (size_t)c * SVOX + hw;
    const size_t gs = (size_t)chunk * SVOX;
    const size_t obase = (size_t)(c0 + c) * SVOX + hw;
    const T* gW = g + gbase;
    const T* gF = g + gs + gbase;
    const T* gR = g + 2 * gs + gbase;
    const T* gX = g + 3 * gs + gbase;

    float C = 0.0f;
#pragma unroll
    for (int i = 0; i < D_DIM; ++i) {
        int d = REV ? (D_DIM - 1 - i) : i;
        float f = sigm(ldf(gF + d * HW));
        float r = sigm(ldf(gR + d * HW));
        float xv = tanhf(ldf(gX + d * HW));
        float wv = tanhf(ldf(gW + d * HW));
        C = (i == 0) ? (1.0f - f) : (f * C + (1.0f - f) * wv);
        float hv = r * C + (1.0f - r) * xv;
        float o = hv + (resid ? ldf(resid + obase + d * HW) : 0.0f);
        stf(out + obase + d * HW, o);
    }
}

// ---------------------------------------------------------------------------
extern "C" void kernel_launch(void* const* d_in, const int* in_sizes, int n_in,
                              void* d_out, int out_size, void* d_ws, size_t ws_size,
                              hipStream_t stream) {
    const float* x      = (const float*)d_in[0];
    const float* w_head = (const float*)d_in[1];  // (96, 1, 27)
    const float* w_e0   = (const float*)d_in[2];  // (128, 16, 27)
    const float* w_e1   = (const float*)d_in[3];  // (256, 32, 27)
    const float* w_d0   = (const float*)d_in[4];  // (64, 128, 27)  deconv
    const float* w_d1   = (const float*)d_in[5];  // (32, 64, 27)   deconv
    const float* w_tail = (const float*)d_in[6];  // (16, 6, 27)    deconv
    float* out = (float*)d_out;

    bf16* g  = (bf16*)d_ws;               // 48*S (si convs use first 32*S)
    bf16* wt = g + (size_t)32 * SVOX;     // merged weights (0.61M elems)
    bf16* H  = g + (size_t)48 * SVOX;     // 16*S
    bf16* E0 = H + (size_t)16 * SVOX;     // 32*S (d0 in-place)
    bf16* E1 = E0 + (size_t)32 * SVOX;    // 64*S (d1 over dead e1)
    bf16* D0 = E0;
    bf16* D1 = E1;

    dim3 blk(256);
    const dim3 sg8(8 * 36);            // scan grid
    const dim3 mg(H_DIM / 4, D_DIM);   // mfma conv grid: (24 h-slabs, d)

    // 1. head: direct conv 1->96 (Ch=16, 6 groups x 8), do_sru -> H
    //    (uses g[0..48S); wt written only after this completes)
    for (int c0 = 0; c0 < 16; c0 += 8) {
        direct_conv_k<float, 8><<<dim3(9, 31, 6), blk, 0, stream>>>(x, w_head, g, 1, 96, 16, c0, 0);
        do_sru_scan_k<bf16, bf16><<<sg8, blk, 0, stream>>>(g, (const bf16*)nullptr, H, 8, c0);
    }
    // merged weight transform for e0/e1/d0/d1
    wtrans_all_k<<<dim3((608256 + 255) / 256), blk, 0, stream>>>(w_e0, w_e1, w_d0, w_d1, wt);

    // 2. e0: mfma conv 16->128 (4 chunks, CI32=1), si_sru fwd -> E0
    for (int c = 0; c < 4; ++c) {
        conv_mfma_k<1><<<mg, blk, 0, stream>>>(H, wt + (size_t)c * 27648, g, 16);
        si_sru_scan_k<bf16, 0><<<sg8, blk, 0, stream>>>(g, (const bf16*)nullptr, E0, 8, c * 8);
    }
    // 3. e1: mfma conv 32->256 (8 chunks, CI32=1), si_sru rev -> E1
    for (int c = 0; c < 8; ++c) {
        conv_mfma_k<1><<<mg, blk, 0, stream>>>(E0, wt + 110592 + (size_t)c * 27648, g, 32);
        si_sru_scan_k<bf16, 1><<<sg8, blk, 0, stream>>>(g, (const bf16*)nullptr, E1, 8, c * 8);
    }
    // 4. d0: mfma deconv 64->128 (4 chunks, CI32=2), si_sru fwd + e0 -> D0
    for (int c = 0; c < 4; ++c) {
        conv_mfma_k<2><<<mg, blk, 0, stream>>>(E1, wt + 331776 + (size_t)c * 55296, g, 64);
        si_sru_scan_k<bf16, 0><<<sg8, blk, 0, stream>>>(g, E0, D0, 8, c * 8);
    }
    // 5. d1: mfma deconv 32->64 (2 chunks, CI32=1), si_sru rev + h -> D1
    for (int c = 0; c < 2; ++c) {
        conv_mfma_k<1><<<mg, blk, 0, stream>>>(D0, wt + 552960 + (size_t)c * 27648, g, 32);
        si_sru_scan_k<bf16, 1><<<sg8, blk, 0, stream>>>(g, H, D1, 8, c * 8);
    }
    // 6. tail: direct deconv 16->6 (1 group of 6), do_sru + x -> out (fp32)
    direct_conv_k<bf16, 6><<<dim3(9, 31, 1), blk, 0, stream>>>(D1, w_tail, g, 16, 6, 1, 0, 1);
    do_sru_scan_k<bf16, float><<<dim3(36), blk, 0, stream>>>(g, x, out, 1, 0);
}

// Round 8
// 1293.445 us; speedup vs baseline: 16.3305x; 1.2651x over previous
//
#include <hip/hip_runtime.h>
#include <hip/hip_bf16.h>

// NSSNN forward on MI355X. x (1,1,31,96,96) fp32. S = 31*96*96 = 285696.
// Round-8: channel-interleaved i8 layout [ch/8][D][H][W][8] for all bf16
// intermediates -> conv_mfma staging is ONE short8 load per 16B LDS item
// (was 8 scalar 2B loads). Activations fused into conv epilogues. Tail conv
// rebuilt (16x16 tile, i8-staged, 1116 blocks). Scans remapped (c=idx&7).
// Workspace (bf16): g(48*S) | H(16*S) | E0(32*S) | E1(64*S) = 91.4 MB;
// wt (all 4 mfma layers, 608256 elems) at g+32S, written after head.

#define D_DIM 31
#define H_DIM 96
#define W_DIM 96
#define HW (H_DIM * W_DIM)
#define SVOX (D_DIM * HW)

typedef __hip_bfloat16 bf16;
typedef __attribute__((ext_vector_type(8))) short short8;
typedef __attribute__((ext_vector_type(4))) short short4a;
typedef __attribute__((ext_vector_type(4))) float f32x4;

__device__ __forceinline__ float sigm(float v) { return 1.0f / (1.0f + __expf(-v)); }
__device__ __forceinline__ short f2bs(float v) {
    bf16 h = __float2bfloat16(v);
    return *(short*)&h;
}
__device__ __forceinline__ float bs2f(short s) {
    return __uint_as_float(((unsigned)(unsigned short)s) << 16);
}

template <typename T> __device__ __forceinline__ float ldf(const T* p);
template <> __device__ __forceinline__ float ldf<float>(const float* p) { return *p; }
template <> __device__ __forceinline__ float ldf<bf16>(const bf16* p) {
    return __bfloat162float(*p);
}
template <typename T> __device__ __forceinline__ void stf(T* p, float v);
template <> __device__ __forceinline__ void stf<float>(float* p, float v) { *p = v; }
template <> __device__ __forceinline__ void stf<bf16>(bf16* p, float v) {
    *p = __float2bfloat16(v);
}

#define P8 ((size_t)8 * SVOX)  // elems per i8 channel-block

// ---------------------------------------------------------------------------
// Merged weight transform (unchanged from r7):
//   wt[region][chunk][kk][oc_c(32)][ci(cip)] bf16, zero-padded ci>=C_in.
// Regions (elems): e0 [0,110592) e1 [110592,331776) d0 [331776,552960)
//                  d1 [552960,608256)
// ---------------------------------------------------------------------------
__global__ __launch_bounds__(256) void wtrans_all_k(const float* __restrict__ w_e0,
                                                    const float* __restrict__ w_e1,
                                                    const float* __restrict__ w_d0,
                                                    const float* __restrict__ w_d1,
                                                    bf16* __restrict__ wt) {
    int i = blockIdx.x * 256 + threadIdx.x;
    if (i >= 608256) return;
    const float* w;
    int j, C_in, C_out_w, Ch, deconv, cip;
    if (i < 110592)      { w = w_e0; j = i;          C_in = 16; C_out_w = 128; Ch = 32; deconv = 0; cip = 32; }
    else if (i < 331776) { w = w_e1; j = i - 110592; C_in = 32; C_out_w = 256; Ch = 64; deconv = 0; cip = 32; }
    else if (i < 552960) { w = w_d0; j = i - 331776; C_in = 64; C_out_w = 128; Ch = 32; deconv = 1; cip = 64; }
    else                 { w = w_d1; j = i - 552960; C_in = 32; C_out_w = 64;  Ch = 16; deconv = 1; cip = 32; }
    int ci = j % cip;
    int r = j / cip;
    int oc_c = r & 31; r >>= 5;
    int kk = r % 27;
    int chunk = r / 27;
    int oc_w = (oc_c >> 3) * Ch + chunk * 8 + (oc_c & 7);
    float v = 0.0f;
    if (ci < C_in)
        v = deconv ? w[((size_t)ci * C_out_w + oc_w) * 27 + (26 - kk)]
                   : w[((size_t)oc_w * C_in + ci) * 27 + kk];
    wt[i] = __float2bfloat16(v);
}

// ---------------------------------------------------------------------------
// MFMA implicit-GEMM conv v4 (i8 input, i8+activated output).
// Grid (24, 31): block = 4 h-rows at depth d, 32 compact oc (4 gates x 8).
// Staging item (wp,hl,cg): ONE short8 load from x-i8 + one ds_write_b128.
// Per wave per tap: 2 A + 6 B loads -> 12 mfma_f32_16x16x32_bf16.
// Epilogue: si gate act (tanh for gate 0,3; sigm for 1,2), short4 stores.
// ---------------------------------------------------------------------------
template <int CI32>
__global__ __launch_bounds__(256) void conv_mfma_k(const bf16* __restrict__ x,
                                                   const bf16* __restrict__ wt,
                                                   bf16* __restrict__ g, int C_in) {
    constexpr int RS = 40;              // ci slot: 32 + 8 pad (80 B, 16B-aligned)
    constexpr int CIP = CI32 * 32;      // wt ci stride
    __shared__ short row[6 * 98 * RS];  // 47,040 B -> 3 blocks/CU

    const int t = threadIdx.x;
    const int lane = t & 63, wave = t >> 6;
    const int l15 = lane & 15, g4 = lane >> 4;
    const int h0 = blockIdx.x * 4, d = blockIdx.y;
    const short* xs = (const short*)x;

    f32x4 acc[6][2];
#pragma unroll
    for (int m = 0; m < 6; ++m)
#pragma unroll
        for (int n = 0; n < 2; ++n) acc[m][n] = (f32x4){0.f, 0.f, 0.f, 0.f};

    for (int kd = 0; kd < 3; ++kd) {
        const int dd = d + kd - 1;
        if ((unsigned)dd >= D_DIM) continue;  // block-uniform
        for (int cb = 0; cb < CI32; ++cb) {
            __syncthreads();
            // stage slab: (wp 98, hl 6, cg 4) = 2352 items; 1 short8 load + 1 b128 write
            for (int i = t; i < 98 * 6 * 4; i += 256) {
                int wp = i % 98;
                int j = i / 98;
                int hl = j % 6;
                int cg = j / 6;
                int hh = h0 + hl - 1;
                int gw = wp - 1;
                const int cblk = cb * 4 + cg;  // input ch8 block
                short8 v = {0, 0, 0, 0, 0, 0, 0, 0};
                if ((unsigned)hh < H_DIM && (unsigned)gw < W_DIM && cblk * 8 < C_in)
                    v = *(const short8*)(xs + (size_t)cblk * P8 +
                                         ((size_t)dd * HW + hh * W_DIM + gw) * 8);
                *(short8*)(row + ((size_t)hl * 98 + wp) * RS + cg * 8) = v;
            }
            __syncthreads();

            const bf16* wa = wt + (size_t)l15 * CIP + cb * 32 + g4 * 8;
#pragma unroll
            for (int kh = 0; kh < 3; ++kh) {
#pragma unroll
                for (int kw = 0; kw < 3; ++kw) {
                    const int kk = (kd * 3 + kh) * 3 + kw;
                    const size_t arow = (size_t)kk * 32 * CIP;
                    short8 a0 = *(const short8*)(wa + arow);
                    short8 a1 = *(const short8*)(wa + arow + (size_t)16 * CIP);
                    const int boff = ((wave + kh) * 98 + l15 + kw) * RS + g4 * 8;
#pragma unroll
                    for (int m = 0; m < 6; ++m) {
                        short8 b = *(const short8*)(row + boff + (m * 16) * RS);
                        acc[m][0] = __builtin_amdgcn_mfma_f32_16x16x32_bf16(a0, b, acc[m][0], 0, 0, 0);
                        acc[m][1] = __builtin_amdgcn_mfma_f32_16x16x32_bf16(a1, b, acc[m][1], 0, 0, 0);
                    }
                }
            }
        }
    }

    // Epilogue: oc_local = n*16 + g4*4 + r -> gate = n*2 + (g4>>1), sub = (g4&1)*4 + r
    // si gates: [Wx(0) tanh, ft(1) sigm, rt(2) sigm, X(3) tanh]
    const int hy = h0 + wave;
    short* gs = (short*)g;
#pragma unroll
    for (int m = 0; m < 6; ++m) {
        const int wx = m * 16 + l15;
        const size_t dhw = (size_t)d * HW + hy * W_DIM + wx;
#pragma unroll
        for (int n = 0; n < 2; ++n) {
            const int gate = n * 2 + (g4 >> 1);
            const bool th = (gate == 0 || gate == 3);
            short4a pack;
#pragma unroll
            for (int r = 0; r < 4; ++r) {
                float a = acc[m][n][r];
                pack[r] = f2bs(th ? tanhf(a) : sigm(a));
            }
            *(short4a*)(gs + (size_t)gate * P8 + dhw * 8 + (g4 & 1) * 4) = pack;
        }
    }
}

// ---------------------------------------------------------------------------
// Head conv: direct 3x3x3, C_in=1 (x fp32 plain), 32x32 tile, 2x2 microtile,
// 8 oc of gate group blockIdx.z. Output: g i8 block gidx, ACTIVATED.
// head gates: [Wx(0) tanh, ft(1), ft2(2), rt(3), rt2(4) sigm, X(5) tanh]
// ---------------------------------------------------------------------------
__global__ __launch_bounds__(256) void head_conv_k(const float* __restrict__ x,
                                                   const float* __restrict__ w,
                                                   bf16* __restrict__ g, int c0) {
    __shared__ float tile[3][34][36];
    __shared__ float wsh[8 * 27];

    const int t = threadIdx.x;
    const int lx = t & 15;
    const int ly = t >> 4;
    const int tbx = (blockIdx.x % 3) * 32;
    const int tby = (blockIdx.x / 3) * 32;
    const int d = blockIdx.y;
    const int gidx = blockIdx.z;
    const int ocw0 = gidx * 16 + c0;

    if (t < 8 * 27) wsh[t] = w[(ocw0 + t / 27) * 27 + (t % 27)];

    for (int i = t; i < 3 * 34 * 34; i += 256) {
        int dz = i / 1156;
        int rem = i - dz * 1156;
        int r = rem / 34;
        int c = rem - r * 34;
        int gd = d + dz - 1;
        int gy = tby + r - 1;
        int gx = tbx + c - 1;
        float v = 0.0f;
        if ((unsigned)gd < D_DIM && (unsigned)gy < H_DIM && (unsigned)gx < W_DIM)
            v = x[((size_t)gd * H_DIM + gy) * W_DIM + gx];
        tile[dz][r][c] = v;
    }
    __syncthreads();

    float acc[8][4];
#pragma unroll
    for (int o = 0; o < 8; ++o)
#pragma unroll
        for (int p = 0; p < 4; ++p) acc[o][p] = 0.0f;

#pragma unroll
    for (int kd = 0; kd < 3; ++kd)
#pragma unroll
        for (int kh = 0; kh < 3; ++kh) {
            float wv[8][3];
#pragma unroll
            for (int o = 0; o < 8; ++o)
#pragma unroll
                for (int kw = 0; kw < 3; ++kw)
                    wv[o][kw] = wsh[o * 27 + (kd * 3 + kh) * 3 + kw];
            const int r0 = ly * 2 + kh;
            float v0[4], v1[4];
#pragma unroll
            for (int c = 0; c < 4; ++c) {
                v0[c] = tile[kd][r0][lx * 2 + c];
                v1[c] = tile[kd][r0 + 1][lx * 2 + c];
            }
#pragma unroll
            for (int kw = 0; kw < 3; ++kw)
#pragma unroll
                for (int o = 0; o < 8; ++o) {
                    acc[o][0] = fmaf(v0[kw],     wv[o][kw], acc[o][0]);
                    acc[o][1] = fmaf(v0[kw + 1], wv[o][kw], acc[o][1]);
                    acc[o][2] = fmaf(v1[kw],     wv[o][kw], acc[o][2]);
                    acc[o][3] = fmaf(v1[kw + 1], wv[o][kw], acc[o][3]);
                }
        }

    const bool th = (gidx == 0 || gidx == 5);
    const int hy = tby + ly * 2, wx = tbx + lx * 2;
    short* gs = (short*)g;
#pragma unroll
    for (int p = 0; p < 4; ++p) {
        const int py = hy + (p >> 1), px = wx + (p & 1);
        short8 pack;
#pragma unroll
        for (int o = 0; o < 8; ++o) {
            float a = acc[o][p];
            pack[o] = f2bs(th ? tanhf(a) : sigm(a));
        }
        *(short8*)(gs + (size_t)gidx * P8 + ((size_t)d * HW + py * W_DIM + px) * 8) = pack;
    }
}

// ---------------------------------------------------------------------------
// Tail conv: deconv 16->6, D1 i8 input, 16x16 tile (1 px/thread), output g
// PLAIN [6][S] bf16, ACTIVATED (gates 0,5 tanh; 1-4 sigm). Grid (36,31).
// ---------------------------------------------------------------------------
__global__ __launch_bounds__(256) void tail_conv_k(const bf16* __restrict__ x,
                                                   const float* __restrict__ w,
                                                   bf16* __restrict__ g) {
    __shared__ short tile[3][18][18][8];  // 15.2 KB
    __shared__ float wsh[8 * 6 * 27];     // 5.1 KB

    const int t = threadIdx.x;
    const int lx = t & 15;
    const int ly = t >> 4;
    const int tbx = (blockIdx.x % 6) * 16;
    const int tby = (blockIdx.x / 6) * 16;
    const int d = blockIdx.y;
    const short* xs = (const short*)x;

    float acc[6] = {0.f, 0.f, 0.f, 0.f, 0.f, 0.f};

    for (int cb = 0; cb < 2; ++cb) {
        __syncthreads();
        // weights: ci = cb*8+u; deconv flip: w[(ci*6 + o)*27 + 26-k]
        for (int i = t; i < 8 * 6 * 27; i += 256) {
            int u = i / 162, rem = i % 162, o = rem / 27, k = rem % 27;
            wsh[i] = w[((cb * 8 + u) * 6 + o) * 27 + (26 - k)];
        }
        for (int i = t; i < 3 * 18 * 18; i += 256) {
            int dz = i / 324;
            int rem = i % 324;
            int r = rem / 18;
            int cc = rem % 18;
            int gd = d + dz - 1;
            int gy = tby + r - 1;
            int gx = tbx + cc - 1;
            short8 v = {0, 0, 0, 0, 0, 0, 0, 0};
            if ((unsigned)gd < D_DIM && (unsigned)gy < H_DIM && (unsigned)gx < W_DIM)
                v = *(const short8*)(xs + (size_t)cb * P8 +
                                     ((size_t)gd * HW + gy * W_DIM + gx) * 8);
            *(short8*)&tile[dz][r][cc][0] = v;
        }
        __syncthreads();

#pragma unroll
        for (int kd = 0; kd < 3; ++kd)
#pragma unroll
            for (int kh = 0; kh < 3; ++kh)
#pragma unroll
                for (int kw = 0; kw < 3; ++kw) {
                    short8 tv = *(short8*)&tile[kd][ly + kh][lx + kw][0];
                    const int k = (kd * 3 + kh) * 3 + kw;
#pragma unroll
                    for (int u = 0; u < 8; ++u) {
                        float xv = bs2f(tv[u]);
#pragma unroll
                        for (int o = 0; o < 6; ++o)
                            acc[o] = fmaf(xv, wsh[(u * 6 + o) * 27 + k], acc[o]);
                    }
                }
    }

    const size_t dhw = (size_t)d * HW + (tby + ly) * W_DIM + (tbx + lx);
#pragma unroll
    for (int o = 0; o < 6; ++o) {
        const bool th = (o == 0 || o == 5);
        stf(g + (size_t)o * SVOX + dhw, th ? tanhf(acc[o]) : sigm(acc[o]));
    }
}

// ---------------------------------------------------------------------------
// si_sru scan (i8, pre-activated gates [Wx, f, r, X]). Thread: c=idx&7,
// hw=idx>>3. outblk = c0>>3. Safe in-place when out==resid.
// ---------------------------------------------------------------------------
template <int REV>
__global__ __launch_bounds__(256) void si_sru_scan_k(const bf16* __restrict__ g,
                                                     const bf16* __restrict__ resid,
                                                     bf16* __restrict__ out, int outblk) {
    const int idx = blockIdx.x * 256 + threadIdx.x;
    const int c = idx & 7;
    const size_t hw = (size_t)(idx >> 3);

    const bf16* oW = g;
    const bf16* oF = g + P8;
    const bf16* oR = g + 2 * P8;
    const bf16* oX = g + 3 * P8;
    const size_t ob = (size_t)outblk * P8;

    float C = 0.0f;
#pragma unroll
    for (int i = 0; i < D_DIM; ++i) {
        const int d = REV ? (D_DIM - 1 - i) : i;
        const size_t off = ((size_t)d * HW + hw) * 8 + c;
        float f = ldf(oF + off);
        float r = ldf(oR + off);
        float xv = ldf(oX + off);
        float wv = ldf(oW + off);
        C = (i == 0) ? (1.0f - f) : (f * C + (1.0f - f) * wv);
        float hv = r * C + (1.0f - r) * xv;
        float o = hv + (resid ? ldf(resid + ob + off) : 0.0f);
        stf(out + ob + off, o);
    }
}

// ---------------------------------------------------------------------------
// do_sru scan for head (i8, pre-activated gates [Wx,f,f2,r,r2,X]), no resid.
// ---------------------------------------------------------------------------
__global__ __launch_bounds__(256) void do_sru_scan_k(const bf16* __restrict__ g,
                                                     bf16* __restrict__ out, int outblk) {
    const int idx = blockIdx.x * 256 + threadIdx.x;
    const int c = idx & 7;
    const size_t hw = (size_t)(idx >> 3);
    const size_t ob = (size_t)outblk * P8;

    float hbuf[D_DIM];
    float C = 0.0f;
#pragma unroll
    for (int d = 0; d < D_DIM; ++d) {
        const size_t off = ((size_t)d * HW + hw) * 8 + c;
        float f = ldf(g + P8 + off);
        float r = ldf(g + 3 * P8 + off);
        float xv = ldf(g + 5 * P8 + off);
        float wv = ldf(g + off);
        C = (d == 0) ? (1.0f - f) : (f * C + (1.0f - f) * wv);
        hbuf[d] = r * C + (1.0f - r) * xv;
    }
#pragma unroll
    for (int i = 0; i < D_DIM; ++i) {
        const int d = D_DIM - 1 - i;
        const size_t off = ((size_t)d * HW + hw) * 8 + c;
        float f = ldf(g + 2 * P8 + off);
        float r = ldf(g + 4 * P8 + off);
        float xv = ldf(g + 5 * P8 + off);
        float wv = ldf(g + off);
        C = (i == 0) ? (1.0f - f) : (f * C + (1.0f - f) * wv);
        hbuf[d] += r * C + (1.0f - r) * xv;
    }
#pragma unroll
    for (int d = 0; d < D_DIM; ++d)
        stf(out + ob + ((size_t)d * HW + hw) * 8 + c, hbuf[d]);
}

// ---------------------------------------------------------------------------
// Final do_sru: g plain [6][S] pre-activated, resid = x (fp32), out fp32.
// One thread per hw column.
// ---------------------------------------------------------------------------
__global__ __launch_bounds__(256) void do_sru_final_k(const bf16* __restrict__ g,
                                                      const float* __restrict__ x,
                                                      float* __restrict__ out) {
    const size_t hw = (size_t)(blockIdx.x * 256 + threadIdx.x);

    float hbuf[D_DIM];
    float C = 0.0f;
#pragma unroll
    for (int d = 0; d < D_DIM; ++d) {
        const size_t off = (size_t)d * HW + hw;
        float f = ldf(g + SVOX + off);
        float r = ldf(g + 3 * (size_t)SVOX + off);
        float xv = ldf(g + 5 * (size_t)SVOX + off);
        float wv = ldf(g + off);
        C = (d == 0) ? (1.0f - f) : (f * C + (1.0f - f) * wv);
        hbuf[d] = r * C + (1.0f - r) * xv;
    }
#pragma unroll
    for (int i = 0; i < D_DIM; ++i) {
        const int d = D_DIM - 1 - i;
        const size_t off = (size_t)d * HW + hw;
        float f = ldf(g + 2 * (size_t)SVOX + off);
        float r = ldf(g + 4 * (size_t)SVOX + off);
        float xv = ldf(g + 5 * (size_t)SVOX + off);
        float wv = ldf(g + off);
        C = (i == 0) ? (1.0f - f) : (f * C + (1.0f - f) * wv);
        hbuf[d] += r * C + (1.0f - r) * xv + x[off];
    }
#pragma unroll
    for (int d = 0; d < D_DIM; ++d) out[(size_t)d * HW + hw] = hbuf[d];
}

// ---------------------------------------------------------------------------
extern "C" void kernel_launch(void* const* d_in, const int* in_sizes, int n_in,
                              void* d_out, int out_size, void* d_ws, size_t ws_size,
                              hipStream_t stream) {
    const float* x      = (const float*)d_in[0];
    const float* w_head = (const float*)d_in[1];  // (96, 1, 27)
    const float* w_e0   = (const float*)d_in[2];  // (128, 16, 27)
    const float* w_e1   = (const float*)d_in[3];  // (256, 32, 27)
    const float* w_d0   = (const float*)d_in[4];  // (64, 128, 27)  deconv
    const float* w_d1   = (const float*)d_in[5];  // (32, 64, 27)   deconv
    const float* w_tail = (const float*)d_in[6];  // (16, 6, 27)    deconv
    float* out = (float*)d_out;

    bf16* g  = (bf16*)d_ws;               // 48*S
    bf16* wt = g + (size_t)32 * SVOX;     // merged weights (608256 elems)
    bf16* H  = g + (size_t)48 * SVOX;     // 16*S  (2 blocks)
    bf16* E0 = H + (size_t)16 * SVOX;     // 32*S  (4 blocks; d0 in-place)
    bf16* E1 = E0 + (size_t)32 * SVOX;    // 64*S  (8 blocks; d1 over dead e1)
    bf16* D0 = E0;
    bf16* D1 = E1;

    dim3 blk(256);
    const dim3 sg8(8 * 36);            // scan grid: HW*8/256
    const dim3 mg(H_DIM / 4, D_DIM);   // mfma conv grid

    // 1. head: conv 1->96 (2 chunks x 6 gate groups), do_sru -> H (i8)
    for (int c0 = 0; c0 < 16; c0 += 8) {
        head_conv_k<<<dim3(9, 31, 6), blk, 0, stream>>>(x, w_head, g, c0);
        do_sru_scan_k<<<sg8, blk, 0, stream>>>(g, H, c0 >> 3);
    }
    // merged weight transform for e0/e1/d0/d1 (wt region free after head)
    wtrans_all_k<<<dim3((608256 + 255) / 256), blk, 0, stream>>>(w_e0, w_e1, w_d0, w_d1, wt);

    // 2. e0: mfma conv 16->128 (4 chunks), si_sru fwd -> E0
    for (int c = 0; c < 4; ++c) {
        conv_mfma_k<1><<<mg, blk, 0, stream>>>(H, wt + (size_t)c * 27648, g, 16);
        si_sru_scan_k<0><<<sg8, blk, 0, stream>>>(g, (const bf16*)nullptr, E0, c);
    }
    // 3. e1: mfma conv 32->256 (8 chunks), si_sru rev -> E1
    for (int c = 0; c < 8; ++c) {
        conv_mfma_k<1><<<mg, blk, 0, stream>>>(E0, wt + 110592 + (size_t)c * 27648, g, 32);
        si_sru_scan_k<1><<<sg8, blk, 0, stream>>>(g, (const bf16*)nullptr, E1, c);
    }
    // 4. d0: mfma deconv 64->128 (4 chunks, CI32=2), si_sru fwd + e0 -> D0
    for (int c = 0; c < 4; ++c) {
        conv_mfma_k<2><<<mg, blk, 0, stream>>>(E1, wt + 331776 + (size_t)c * 55296, g, 64);
        si_sru_scan_k<0><<<sg8, blk, 0, stream>>>(g, E0, D0, c);
    }
    // 5. d1: mfma deconv 32->64 (2 chunks), si_sru rev + h -> D1
    for (int c = 0; c < 2; ++c) {
        conv_mfma_k<1><<<mg, blk, 0, stream>>>(D0, wt + 552960 + (size_t)c * 27648, g, 32);
        si_sru_scan_k<1><<<sg8, blk, 0, stream>>>(g, H, D1, c);
    }
    // 6. tail: deconv 16->6 -> g plain [6][S], do_sru + x -> out (fp32)
    tail_conv_k<<<dim3(36, 31), blk, 0, stream>>>(D1, w_tail, g);
    do_sru_final_k<<<dim3(36), blk, 0, stream>>>(g, x, out);
}